// Round 4
// baseline (506.307 us; speedup 1.0000x reference)
//
#include <hip/hip_runtime.h>
#include <hip/hip_cooperative_groups.h>

// EMA recurrence over s for x[4, 4096, 2048] fp32.
// Plan A (cema_coop): single cooperative kernel — phase A computes chunk
//   finals, one grid.sync(), phase B Horners the carry and rescans the
//   chunk from L3-resident x. Saves a kernel boundary + HBM re-read.
// Plan B (fallback, if cooperative launch fails under graph capture):
//   the proven two-pass chunked scan (round-0 baseline, 253 us).
// Both paths use the identical FMA ordering -> bit-identical output.

namespace cg = cooperative_groups;

namespace {

constexpr int B  = 4;
constexpr int S  = 4096;
constexpr int D  = 2048;
constexpr int D4 = D / 4;          // 512 float4 per (b,s) row
constexpr int NCOL4 = B * D4;      // 2048 float4-columns
constexpr int BLOCK = 256;
constexpr int XB = NCOL4 / BLOCK;  // 8 column-blocks

typedef float v4f __attribute__((ext_vector_type(4)));

// Match the reference's fp32 constants exactly.
constexpr float kA  = 0.99f;
constexpr float kOm = (float)(1.0 - 0.99);      // 0.009999999776482582f

// 0.99^L in double, L a power of two (repeated squaring), then round to float.
constexpr double alpha_pow_pow2(int l) {
    double t = 0.99;
    while (l > 1) { t *= t; l >>= 1; }
    return t;
}

// ---------------- Plan A: cooperative fused kernel ----------------

template <int NCHUNK>
__global__ __launch_bounds__(BLOCK, 4)   // <=128 VGPR -> 4 blocks/CU, grid co-resident
void cema_coop(const float4* __restrict__ x, float4* __restrict__ finals,
               float4* __restrict__ out) {
    constexpr int L = S / NCHUNK;
    constexpr float aL = (float)alpha_pow_pow2(L);

    const int xb = blockIdx.x;
    const int c  = xb * BLOCK + threadIdx.x;   // col4 index
    const int j  = blockIdx.y;                 // chunk index
    const int b  = c >> 9;                     // c / D4
    const int d4 = c & (D4 - 1);

    const size_t base = ((size_t)b * S + (size_t)j * L) * D4 + d4;
    const float4* p = x + base;

    // Phase A: local EMA over this chunk (zero init)
    float f0 = 0.f, f1 = 0.f, f2 = 0.f, f3 = 0.f;
#pragma unroll 8
    for (int t = 0; t < L; ++t) {
        float4 v = p[(size_t)t * D4];
        f0 = kA * f0 + kOm * v.x;
        f1 = kA * f1 + kOm * v.y;
        f2 = kA * f2 + kOm * v.z;
        f3 = kA * f3 + kOm * v.w;
    }
    finals[(size_t)j * NCOL4 + c] = make_float4(f0, f1, f2, f3);

    // One grid-wide barrier (finals visible at agent scope)
    __threadfence();
    cg::this_grid().sync();

    // Phase B: carry Horner (ascending — identical numerics to two-pass K2)
    float E0 = 0.f, E1 = 0.f, E2 = 0.f, E3 = 0.f;
    const float4* w = finals + c;
#pragma unroll 4
    for (int i = 0; i < j; ++i) {              // j block-uniform: no divergence
        float4 f = w[(size_t)i * NCOL4];
        E0 = E0 * aL + f.x;
        E1 = E1 * aL + f.y;
        E2 = E2 * aL + f.z;
        E3 = E3 * aL + f.w;
    }

    // Rescan chunk from x (L3-hot) with carry, nontemporal-store out
    v4f* q = (v4f*)(out + base);
#pragma unroll 8
    for (int t = 0; t < L; ++t) {
        float4 v = p[(size_t)t * D4];
        E0 = kA * E0 + kOm * v.x;
        E1 = kA * E1 + kOm * v.y;
        E2 = kA * E2 + kOm * v.z;
        E3 = kA * E3 + kOm * v.w;
        v4f o = {E0, E1, E2, E3};
        __builtin_nontemporal_store(o, &q[(size_t)t * D4]);
    }
}

// ---------------- Plan B: proven two-pass fallback ----------------

template <int NCHUNK>
__global__ __launch_bounds__(BLOCK)
void cema_k1_finals(const float4* __restrict__ x, float4* __restrict__ ws) {
    constexpr int L = S / NCHUNK;
    const int c  = blockIdx.x * BLOCK + threadIdx.x;
    const int j  = blockIdx.y;
    const int b  = c >> 9;
    const int d4 = c & (D4 - 1);

    const size_t base = ((size_t)b * S + (size_t)j * L) * D4 + d4;
    const float4* p = x + base;

    float e0 = 0.f, e1 = 0.f, e2 = 0.f, e3 = 0.f;
#pragma unroll 8
    for (int t = 0; t < L; ++t) {
        float4 v = p[(size_t)t * D4];
        e0 = kA * e0 + kOm * v.x;
        e1 = kA * e1 + kOm * v.y;
        e2 = kA * e2 + kOm * v.z;
        e3 = kA * e3 + kOm * v.w;
    }
    ws[(size_t)j * NCOL4 + c] = make_float4(e0, e1, e2, e3);
}

template <int NCHUNK>
__global__ __launch_bounds__(BLOCK)
void cema_k2_apply(const float4* __restrict__ x, const float4* __restrict__ ws,
                   float4* __restrict__ out) {
    constexpr int L = S / NCHUNK;
    constexpr float aL = (float)alpha_pow_pow2(L);

    const int c  = blockIdx.x * BLOCK + threadIdx.x;
    const int j  = blockIdx.y;
    const int b  = c >> 9;
    const int d4 = c & (D4 - 1);

    float E0 = 0.f, E1 = 0.f, E2 = 0.f, E3 = 0.f;
#pragma unroll 4
    for (int i = 0; i < j; ++i) {
        float4 f = ws[(size_t)i * NCOL4 + c];
        E0 = E0 * aL + f.x;
        E1 = E1 * aL + f.y;
        E2 = E2 * aL + f.z;
        E3 = E3 * aL + f.w;
    }

    const size_t base = ((size_t)b * S + (size_t)j * L) * D4 + d4;
    const float4* p = x + base;
    v4f* q = (v4f*)(out + base);

#pragma unroll 8
    for (int t = 0; t < L; ++t) {
        float4 v = p[(size_t)t * D4];
        E0 = kA * E0 + kOm * v.x;
        E1 = kA * E1 + kOm * v.y;
        E2 = kA * E2 + kOm * v.z;
        E3 = kA * E3 + kOm * v.w;
        v4f o = {E0, E1, E2, E3};
        __builtin_nontemporal_store(o, &q[(size_t)t * D4]);
    }
}

// ---------------- launch ----------------

template <int NCHUNK>
void launch(const float4* x, float4* ws, float4* out, hipStream_t stream) {
    const float4* xa = x;
    float4* fa = ws;
    float4* oa = out;
    void* args[] = { (void*)&xa, (void*)&fa, (void*)&oa };
    hipError_t err = hipLaunchCooperativeKernel(
        (const void*)cema_coop<NCHUNK>, dim3(XB, NCHUNK), dim3(BLOCK),
        args, 0, stream);
    if (err != hipSuccess) {
        (void)hipGetLastError();   // clear sticky error, fall back to two-pass
        dim3 grid(XB, NCHUNK);
        cema_k1_finals<NCHUNK><<<grid, BLOCK, 0, stream>>>(x, ws);
        cema_k2_apply<NCHUNK><<<grid, BLOCK, 0, stream>>>(x, ws, out);
    }
}

} // namespace

extern "C" void kernel_launch(void* const* d_in, const int* in_sizes, int n_in,
                              void* d_out, int out_size, void* d_ws, size_t ws_size,
                              hipStream_t stream) {
    const float4* x  = (const float4*)d_in[0];
    float4* out      = (float4*)d_out;
    float4* ws       = (float4*)d_ws;

    auto need = [](size_t nchunk) {
        return nchunk * (size_t)NCOL4 * sizeof(float4);
    };
    if (ws_size >= need(128))      launch<128>(x, ws, out, stream);
    else if (ws_size >= need(64))  launch<64>(x, ws, out, stream);
    else                           launch<32>(x, ws, out, stream);
}

// Round 5
// 264.423 us; speedup vs baseline: 1.9148x; 1.9148x over previous
//
#include <hip/hip_runtime.h>

// EMA recurrence over s for x[4, 4096, 2048] fp32.
// Three-pass chunked scan, max-occupancy variant. NO in-kernel cross-block
// sync (rounds 1 & 4 proved any gfx950 cross-XCD spin-wait costs ~300 us;
// kernel boundaries cost ~5 us).
//   K1:   NCHUNK=256 chunks (L=16) -> 2048 blocks = 8 blocks/CU = 32 waves/CU
//         (max occupancy; launch_bounds(256,8) caps VGPR at 64).
//   Kmid: sequential scan of chunk finals -> exclusive carries (proven ~5 us).
//   K3:   one carry row + rescan chunk from x (L3-resident), NT-store out.

namespace {

constexpr int B  = 4;
constexpr int S  = 4096;
constexpr int D  = 2048;
constexpr int D4 = D / 4;          // 512 float4 per (b,s) row
constexpr int NCOL4 = B * D4;      // 2048 float4-columns
constexpr int NCOLS = NCOL4 * 4;   // 8192 scalar columns
constexpr int BLOCK = 256;

typedef float v4f __attribute__((ext_vector_type(4)));

// Match the reference's fp32 constants exactly.
constexpr float kA  = 0.99f;
constexpr float kOm = (float)(1.0 - 0.99);      // 0.009999999776482582f

// 0.99^L in double, L a power of two (repeated squaring), then round to float.
constexpr double alpha_pow_pow2(int l) {
    double t = 0.99;
    while (l > 1) { t *= t; l >>= 1; }
    return t;
}

template <int NCHUNK>
__global__ __launch_bounds__(BLOCK, 8)   // VGPR<=64 -> 8 blocks/CU, 32 waves/CU
void cema_k1_finals(const float4* __restrict__ x, float4* __restrict__ finals) {
    constexpr int L = S / NCHUNK;
    const int c  = blockIdx.x * BLOCK + threadIdx.x;   // col4 index
    const int j  = blockIdx.y;                         // chunk index
    const int b  = c >> 9;                             // c / D4
    const int d4 = c & (D4 - 1);

    const size_t base = ((size_t)b * S + (size_t)j * L) * D4 + d4;
    const float4* p = x + base;

    float e0 = 0.f, e1 = 0.f, e2 = 0.f, e3 = 0.f;
#pragma unroll 8
    for (int t = 0; t < L; ++t) {
        float4 v = p[(size_t)t * D4];
        e0 = kA * e0 + kOm * v.x;
        e1 = kA * e1 + kOm * v.y;
        e2 = kA * e2 + kOm * v.z;
        e3 = kA * e3 + kOm * v.w;
    }
    finals[(size_t)j * NCOL4 + c] = make_float4(e0, e1, e2, e3);
}

// Sequential scan over chunk finals -> exclusive carries (one thread per
// scalar column, coalesced rows; loads prefetch ahead of the dependent
// FMA chain). carry[j] = E_{j-1}, identical FMA order to the proven Horner.
template <int NCHUNK>
__global__ __launch_bounds__(BLOCK)
void cema_scan_finals(const float* __restrict__ finals, float* __restrict__ carry) {
    constexpr int L = S / NCHUNK;
    constexpr float aL = (float)alpha_pow_pow2(L);

    const int col = blockIdx.x * BLOCK + threadIdx.x;  // 0..NCOLS-1
    float E = 0.f;
#pragma unroll 8
    for (int j = 0; j < NCHUNK; ++j) {
        float f = finals[(size_t)j * NCOLS + col];
        carry[(size_t)j * NCOLS + col] = E;            // exclusive carry
        E = E * aL + f;
    }
}

template <int NCHUNK>
__global__ __launch_bounds__(BLOCK, 8)   // VGPR<=64 -> 8 blocks/CU, 32 waves/CU
void cema_k3_apply(const float4* __restrict__ x, const float4* __restrict__ carry,
                   float4* __restrict__ out) {
    constexpr int L = S / NCHUNK;

    const int c  = blockIdx.x * BLOCK + threadIdx.x;
    const int j  = blockIdx.y;
    const int b  = c >> 9;
    const int d4 = c & (D4 - 1);

    // One coalesced carry-row read (L2/L3 resident).
    float4 E4 = carry[(size_t)j * NCOL4 + c];
    float E0 = E4.x, E1 = E4.y, E2 = E4.z, E3 = E4.w;

    const size_t base = ((size_t)b * S + (size_t)j * L) * D4 + d4;
    const float4* p = x + base;
    v4f* q = (v4f*)(out + base);

#pragma unroll 8
    for (int t = 0; t < L; ++t) {
        float4 v = p[(size_t)t * D4];
        E0 = kA * E0 + kOm * v.x;
        E1 = kA * E1 + kOm * v.y;
        E2 = kA * E2 + kOm * v.z;
        E3 = kA * E3 + kOm * v.w;
        v4f o = {E0, E1, E2, E3};
        __builtin_nontemporal_store(o, &q[(size_t)t * D4]);
    }
}

template <int NCHUNK>
void launch(const float4* x, float4* ws, float4* out, hipStream_t stream) {
    float4* finals = ws;
    float4* carry  = ws + (size_t)NCHUNK * NCOL4;

    dim3 grid(NCOL4 / BLOCK, NCHUNK);
    cema_k1_finals<NCHUNK><<<grid, BLOCK, 0, stream>>>(x, finals);
    cema_scan_finals<NCHUNK><<<dim3(NCOLS / BLOCK), BLOCK, 0, stream>>>(
        (const float*)finals, (float*)carry);
    cema_k3_apply<NCHUNK><<<grid, BLOCK, 0, stream>>>(x, carry, out);
}

} // namespace

extern "C" void kernel_launch(void* const* d_in, const int* in_sizes, int n_in,
                              void* d_out, int out_size, void* d_ws, size_t ws_size,
                              hipStream_t stream) {
    const float4* x  = (const float4*)d_in[0];
    float4* out      = (float4*)d_out;
    float4* ws       = (float4*)d_ws;

    auto need = [](size_t nchunk) {
        return 2 * nchunk * (size_t)NCOL4 * sizeof(float4);
    };
    if (ws_size >= need(256))      launch<256>(x, ws, out, stream);
    else if (ws_size >= need(128)) launch<128>(x, ws, out, stream);
    else                           launch<64>(x, ws, out, stream);
}

// Round 6
// 254.111 us; speedup vs baseline: 1.9925x; 1.0406x over previous
//
#include <hip/hip_runtime.h>

// EMA recurrence over s for x[4, 4096, 2048] fp32.
// Two-pass chunked scan (round-0 proven structure) with CONTIGUOUS per-block
// streaming: one row of D is 512 float4 = 2x block width, so each thread
// owns TWO column quads (t, t+256) and block (b, j) sweeps its chunk's rows
// in order — every block reads/writes one linear 256-KiB range (matching the
// access pattern of the 6.7 TB/s rocclr fill) instead of 4-KiB bursts at
// 8-KiB stride. FMA order per column identical to round-0 -> same absmax.
//   K1: per-chunk local EMA (zero init) -> finals[j] rows.
//   K2: ascending Horner over finals (block-uniform j, L3-served, proven
//       free) -> carry, then rescan chunk from L3-resident x, NT-store out.
// No in-kernel cross-block sync (rounds 1 & 4: ~300 us penalty on gfx950).

namespace {

constexpr int B  = 4;
constexpr int S  = 4096;
constexpr int D  = 2048;
constexpr int D4 = D / 4;          // 512 float4 per (b,s) row
constexpr int NCOL4 = B * D4;      // 2048 float4-columns
constexpr int BLOCK = 256;         // = D4/2: each thread owns 2 column quads

typedef float v4f __attribute__((ext_vector_type(4)));

// Match the reference's fp32 constants exactly.
constexpr float kA  = 0.99f;
constexpr float kOm = (float)(1.0 - 0.99);      // 0.009999999776482582f

// 0.99^L in double, L a power of two (repeated squaring), then round to float.
constexpr double alpha_pow_pow2(int l) {
    double t = 0.99;
    while (l > 1) { t *= t; l >>= 1; }
    return t;
}

template <int NCHUNK>
__global__ __launch_bounds__(BLOCK, 2)
void cema_k1_finals(const float4* __restrict__ x, float4* __restrict__ finals) {
    constexpr int L = S / NCHUNK;
    const int t  = threadIdx.x;
    const int bb = blockIdx.x;                 // batch index
    const int j  = blockIdx.y;                 // chunk index

    // Block's chunk: rows [j*L, (j+1)*L) of batch bb — contiguous L*8KiB.
    const size_t base = ((size_t)bb * S + (size_t)j * L) * D4;
    const float4* p = x + base;

    float a0 = 0.f, a1 = 0.f, a2 = 0.f, a3 = 0.f;   // column quad t
    float b0 = 0.f, b1 = 0.f, b2 = 0.f, b3 = 0.f;   // column quad t+256
#pragma unroll 8
    for (int s = 0; s < L; ++s) {
        float4 u = p[(size_t)s * D4 + t];
        float4 v = p[(size_t)s * D4 + t + BLOCK];
        a0 = kA * a0 + kOm * u.x;
        a1 = kA * a1 + kOm * u.y;
        a2 = kA * a2 + kOm * u.z;
        a3 = kA * a3 + kOm * u.w;
        b0 = kA * b0 + kOm * v.x;
        b1 = kA * b1 + kOm * v.y;
        b2 = kA * b2 + kOm * v.z;
        b3 = kA * b3 + kOm * v.w;
    }
    const size_t frow = (size_t)j * NCOL4 + (size_t)bb * D4;
    finals[frow + t]         = make_float4(a0, a1, a2, a3);
    finals[frow + t + BLOCK] = make_float4(b0, b1, b2, b3);
}

template <int NCHUNK>
__global__ __launch_bounds__(BLOCK, 2)
void cema_k2_apply(const float4* __restrict__ x, const float4* __restrict__ finals,
                   float4* __restrict__ out) {
    constexpr int L = S / NCHUNK;
    constexpr float aL = (float)alpha_pow_pow2(L);

    const int t  = threadIdx.x;
    const int bb = blockIdx.x;
    const int j  = blockIdx.y;

    // Carry into chunk j: ascending Horner over finals rows (j block-uniform;
    // reads coalesced; table is L3-resident — proven free in round 0).
    float A0 = 0.f, A1 = 0.f, A2 = 0.f, A3 = 0.f;
    float B0 = 0.f, B1 = 0.f, B2 = 0.f, B3 = 0.f;
    const float4* w = finals + (size_t)bb * D4;
#pragma unroll 4
    for (int i = 0; i < j; ++i) {
        float4 f = w[(size_t)i * NCOL4 + t];
        float4 g = w[(size_t)i * NCOL4 + t + BLOCK];
        A0 = A0 * aL + f.x;  A1 = A1 * aL + f.y;
        A2 = A2 * aL + f.z;  A3 = A3 * aL + f.w;
        B0 = B0 * aL + g.x;  B1 = B1 * aL + g.y;
        B2 = B2 * aL + g.z;  B3 = B3 * aL + g.w;
    }

    const size_t base = ((size_t)bb * S + (size_t)j * L) * D4;
    const float4* p = x + base;
    v4f* q = (v4f*)(out + base);

#pragma unroll 8
    for (int s = 0; s < L; ++s) {
        float4 u = p[(size_t)s * D4 + t];
        float4 v = p[(size_t)s * D4 + t + BLOCK];
        A0 = kA * A0 + kOm * u.x;
        A1 = kA * A1 + kOm * u.y;
        A2 = kA * A2 + kOm * u.z;
        A3 = kA * A3 + kOm * u.w;
        B0 = kA * B0 + kOm * v.x;
        B1 = kA * B1 + kOm * v.y;
        B2 = kA * B2 + kOm * v.z;
        B3 = kA * B3 + kOm * v.w;
        v4f oa = {A0, A1, A2, A3};
        v4f ob = {B0, B1, B2, B3};
        __builtin_nontemporal_store(oa, &q[(size_t)s * D4 + t]);
        __builtin_nontemporal_store(ob, &q[(size_t)s * D4 + t + BLOCK]);
    }
}

template <int NCHUNK>
void launch(const float4* x, float4* ws, float4* out, hipStream_t stream) {
    dim3 grid(B, NCHUNK);
    cema_k1_finals<NCHUNK><<<grid, BLOCK, 0, stream>>>(x, ws);
    cema_k2_apply<NCHUNK><<<grid, BLOCK, 0, stream>>>(x, ws, out);
}

} // namespace

extern "C" void kernel_launch(void* const* d_in, const int* in_sizes, int n_in,
                              void* d_out, int out_size, void* d_ws, size_t ws_size,
                              hipStream_t stream) {
    const float4* x  = (const float4*)d_in[0];
    float4* out      = (float4*)d_out;
    float4* ws       = (float4*)d_ws;

    const size_t per_chunk = (size_t)NCOL4 * sizeof(float4);
    if (ws_size >= 128 * per_chunk)      launch<128>(x, ws, out, stream);
    else if (ws_size >= 64 * per_chunk)  launch<64>(x, ws, out, stream);
    else                                 launch<32>(x, ws, out, stream);
}

// Round 7
// 251.881 us; speedup vs baseline: 2.0101x; 1.0089x over previous
//
#include <hip/hip_runtime.h>

// EMA recurrence over s for x[4, 4096, 2048] fp32.
// Two-pass chunked scan (round-0 proven structure, 253.2 us) with ONE change:
// K2 stages 16 float4 per thread in registers — 16 batched loads, FMA chain,
// 16 batched NT stores — coarsening the HBM read/write direction-interleave
// from ~8 KB/wave to ~16 KB/wave per direction (bus-turnaround hypothesis,
// the last untested mechanism; all parallelism/pattern levers proved null in
// rounds 2/4/5/6). Per-column FMA order unchanged -> bit-identical output.
//   K1: per-(col4, chunk) local EMA (zero init) -> chunk finals in ws.
//   K2: ascending Horner carry over finals (block-uniform j, L3-served,
//       proven free) + staged rescan of chunk from L3-resident x, NT out.
// No in-kernel cross-block sync (rounds 1 & 4: ~300 us cross-XCD penalty).

namespace {

constexpr int B  = 4;
constexpr int S  = 4096;
constexpr int D  = 2048;
constexpr int D4 = D / 4;          // 512 float4 per (b,s) row
constexpr int NCOL4 = B * D4;      // 2048 float4-columns
constexpr int BLOCK = 256;
constexpr int G = 16;              // staging depth (float4 per thread per group)

typedef float v4f __attribute__((ext_vector_type(4)));

// Match the reference's fp32 constants exactly.
constexpr float kA  = 0.99f;
constexpr float kOm = (float)(1.0 - 0.99);      // 0.009999999776482582f

// 0.99^L in double, L a power of two (repeated squaring), then round to float.
constexpr double alpha_pow_pow2(int l) {
    double t = 0.99;
    while (l > 1) { t *= t; l >>= 1; }
    return t;
}

template <int NCHUNK>
__global__ __launch_bounds__(BLOCK)
void cema_k1_finals(const float4* __restrict__ x, float4* __restrict__ ws) {
    constexpr int L = S / NCHUNK;
    const int c  = blockIdx.x * BLOCK + threadIdx.x;   // col4 index
    const int j  = blockIdx.y;                         // chunk index
    const int b  = c >> 9;                             // c / D4
    const int d4 = c & (D4 - 1);

    const size_t base = ((size_t)b * S + (size_t)j * L) * D4 + d4;
    const float4* p = x + base;

    float e0 = 0.f, e1 = 0.f, e2 = 0.f, e3 = 0.f;
#pragma unroll 8
    for (int t = 0; t < L; ++t) {
        float4 v = p[(size_t)t * D4];
        e0 = kA * e0 + kOm * v.x;
        e1 = kA * e1 + kOm * v.y;
        e2 = kA * e2 + kOm * v.z;
        e3 = kA * e3 + kOm * v.w;
    }
    ws[(size_t)j * NCOL4 + c] = make_float4(e0, e1, e2, e3);
}

template <int NCHUNK>
__global__ __launch_bounds__(BLOCK, 2)   // VGPR cap 256: room for 16-float4 stage
void cema_k2_apply(const float4* __restrict__ x, const float4* __restrict__ ws,
                   float4* __restrict__ out) {
    constexpr int L = S / NCHUNK;
    static_assert(L % G == 0, "chunk length must be a multiple of staging depth");
    constexpr float aL = (float)alpha_pow_pow2(L);

    const int c  = blockIdx.x * BLOCK + threadIdx.x;
    const int j  = blockIdx.y;
    const int b  = c >> 9;
    const int d4 = c & (D4 - 1);

    // Carry into chunk j: ascending Horner over finals (identical numerics
    // to round-0; j block-uniform, table L2/L3-resident, proven free).
    float E0 = 0.f, E1 = 0.f, E2 = 0.f, E3 = 0.f;
#pragma unroll 4
    for (int i = 0; i < j; ++i) {
        float4 f = ws[(size_t)i * NCOL4 + c];
        E0 = E0 * aL + f.x;
        E1 = E1 * aL + f.y;
        E2 = E2 * aL + f.z;
        E3 = E3 * aL + f.w;
    }

    const size_t base = ((size_t)b * S + (size_t)j * L) * D4 + d4;
    const float4* p = x + base;
    v4f* q = (v4f*)(out + base);

    // Staged rescan: G batched loads -> FMA chain -> G batched NT stores.
    // All v[] indices compile-time constant (full unroll) -> registers.
    for (int g = 0; g < L / G; ++g) {
        const size_t off = (size_t)g * G;
        float4 v[G];
#pragma unroll
        for (int t = 0; t < G; ++t)
            v[t] = p[(off + t) * D4];
#pragma unroll
        for (int t = 0; t < G; ++t) {
            E0 = kA * E0 + kOm * v[t].x;
            E1 = kA * E1 + kOm * v[t].y;
            E2 = kA * E2 + kOm * v[t].z;
            E3 = kA * E3 + kOm * v[t].w;
            v[t] = make_float4(E0, E1, E2, E3);
        }
#pragma unroll
        for (int t = 0; t < G; ++t) {
            v4f o = {v[t].x, v[t].y, v[t].z, v[t].w};
            __builtin_nontemporal_store(o, &q[(off + t) * D4]);
        }
    }
}

template <int NCHUNK>
void launch(const float4* x, float4* ws, float4* out, hipStream_t stream) {
    dim3 grid(NCOL4 / BLOCK, NCHUNK);
    cema_k1_finals<NCHUNK><<<grid, BLOCK, 0, stream>>>(x, ws);
    cema_k2_apply<NCHUNK><<<grid, BLOCK, 0, stream>>>(x, ws, out);
}

} // namespace

extern "C" void kernel_launch(void* const* d_in, const int* in_sizes, int n_in,
                              void* d_out, int out_size, void* d_ws, size_t ws_size,
                              hipStream_t stream) {
    const float4* x  = (const float4*)d_in[0];
    float4* out      = (float4*)d_out;
    float4* ws       = (float4*)d_ws;

    const size_t per_chunk = (size_t)NCOL4 * sizeof(float4);
    if (ws_size >= 128 * per_chunk)      launch<128>(x, ws, out, stream);
    else if (ws_size >= 64 * per_chunk)  launch<64>(x, ws, out, stream);
    else                                 launch<32>(x, ws, out, stream);
}